// Round 1
// baseline (590.624 us; speedup 1.0000x reference)
//
#include <hip/hip_runtime.h>
#include <hip/hip_bf16.h>

#define NN 100000
#define DD 64
#define EE 400000
#define TT 5

#define NSPLIT 16                /* edge-stream splits (inner sort key) */
#define ESL (EE / NSPLIT)        /* 25,000 edges per split slice */
#define CH 16                    /* node chunks per t (exclusive bin ownership) */
#define BPC 6250                 /* NN/CH exact */
#define BPCP 6272                /* padded region (98 x 64B lines) */
#define C2STRIDE ((size_t)TT * CH * BPCP)   /* u8 elems per split plane = 501,760 */

#define SCAN_TOTAL 500000        /* T*N bins */
#define SCAN_T 256
#define SCAN_PER 1024            /* bins per scan block */
#define SCAN_B 512               /* 512*1024 >= 500000 */

#define NB 64                    /* nodes per k_edge2 block (exclusive out ownership) */
#define NBLK ((NN + NB - 1) / NB)   /* 1563 */

typedef __bf16 bf16x8 __attribute__((ext_vector_type(8)));
typedef float  f32x4  __attribute__((ext_vector_type(4)));

// ws layout (bytes) — total 40,914,240
#define OFF_XBF  0u            // N*D ushort      = 12,800,000
#define OFF_WT   12800000u     // T*64*128 ushort = 81,920
#define OFF_CTOT 12881920u     // T*N u32 (cnt_tot) = 2,000,000
#define OFF_WGT  14881920u     // T f32 (pad 64)
#define OFF_CUR  14881984u     // T*N u32 (scan of totals) = 2,000,000
#define OFF_BS   16881984u     // 512 u32 (pad 2048)
#define OFF_BO   16884032u     // 512 u32 (pad 2048)
#define OFF_CNT2 16886080u     // u8[NSPLIT][T][CH][BPCP] = 8,028,160
#define OFF_DST  24914240u     // 2M int (sorted dst) = 8,000,000
#define OFF_SEG  32914240u     // 2M int (seg src)    = 8,000,000 -> 40,914,240

__device__ __forceinline__ unsigned short f2bf(float f) {
    union { float f; unsigned u; } v; v.f = f;
    unsigned u = v.u;
    return (unsigned short)((u + 0x7FFFu + ((u >> 16) & 1u)) >> 16);  // RNE
}

// ---------------- Phase 1: init / convert (out zeroing dropped: k_edge2 writes
// every out line exactly once, non-atomically) --------------------------------
__global__ void k_init(const float* __restrict__ x, const float* __restrict__ W,
                       const float* __restrict__ ea,
                       unsigned short* __restrict__ xbf, unsigned short* __restrict__ wT,
                       float* __restrict__ wgt) {
    int i = blockIdx.x * blockDim.x + threadIdx.x;   // grid covers N*D exactly
    if (i < NN * DD) {
        xbf[i] = f2bf(x[i]);
    }
    if (i < TT * 128 * 64) {
        int t = i >> 13;          // /8192
        int rem = i & 8191;
        int d = rem >> 7;         // /128
        int k = rem & 127;
        wT[i] = f2bf(W[t * 8192 + k * 64 + d]);   // wT[t][d][k] = W[t][k][d]
    }
    if (i == 0) {
        float m = -1e30f;
        for (int t = 0; t < TT; t++) m = fmaxf(m, ea[t]);
        float e[TT]; float s = 0.0f;
        for (int t = 0; t < TT; t++) { e[t] = __expf(ea[t] - m); s += e[t]; }
        for (int t = 0; t < TT; t++) wgt[t] = e[t] / s;
    }
}

// ---------------- Phase 2: chunk+split histogram (no global atomics) ---------
__global__ __launch_bounds__(256) void k_count_c(const int* __restrict__ edges,
                                                 unsigned char* __restrict__ cnt2) {
    const int chunk = blockIdx.x, split = blockIdx.y, t = blockIdx.z;
    const int lo = chunk * BPC;
    __shared__ unsigned hist[BPC];
    for (int i = threadIdx.x; i < BPC; i += 256) hist[i] = 0u;
    __syncthreads();
    const int4* srcp = reinterpret_cast<const int4*>(edges + (size_t)t * 2 * EE + split * ESL);
    for (int i = threadIdx.x; i < ESL / 4; i += 256) {
        int4 v = srcp[i];
        unsigned ux = v.x - lo, uy = v.y - lo, uz = v.z - lo, uw = v.w - lo;
        if (ux < BPC) atomicAdd(&hist[ux], 1u);
        if (uy < BPC) atomicAdd(&hist[uy], 1u);
        if (uz < BPC) atomicAdd(&hist[uz], 1u);
        if (uw < BPC) atomicAdd(&hist[uw], 1u);
    }
    __syncthreads();
    unsigned char* outp = cnt2 + split * C2STRIDE + ((size_t)t * CH + chunk) * BPCP;
    for (int i = threadIdx.x; i < BPC; i += 256) outp[i] = (unsigned char)hist[i];
}

// ---------------- Phase 2b: per-bin totals (sum of 16 u8 planes) + scan ------
__global__ void k_scan1(const unsigned char* __restrict__ cnt2,
                        unsigned* __restrict__ cnt_tot,
                        unsigned* __restrict__ cur, unsigned* __restrict__ bsum) {
    __shared__ unsigned s[SCAN_T];
    const int b = blockIdx.x, tid = threadIdx.x;
    const int base = b * SCAN_PER + tid * 4;   // bin index (500000 % 4 == 0)
    unsigned tot[4] = {0u, 0u, 0u, 0u};
    if (base < SCAN_TOTAL) {
#pragma unroll
        for (int j = 0; j < 4; j++) {
            int g = base + j;
            int t = g / NN, n = g - t * NN;
            int chunk = n / BPC, r = n - chunk * BPC;
            size_t o = ((size_t)t * CH + chunk) * BPCP + r;
            unsigned acc = 0u;
#pragma unroll
            for (int sp = 0; sp < NSPLIT; sp++)
                acc += cnt2[sp * C2STRIDE + o];
            tot[j] = acc;
        }
        *reinterpret_cast<uint4*>(cnt_tot + base) = make_uint4(tot[0], tot[1], tot[2], tot[3]);
    }
    const unsigned tsum = tot[0] + tot[1] + tot[2] + tot[3];
    s[tid] = tsum;
    __syncthreads();
    unsigned inc = tsum;
    for (int d = 1; d < SCAN_T; d <<= 1) {
        unsigned add = (tid >= d) ? s[tid - d] : 0u;
        __syncthreads();
        inc += add;
        s[tid] = inc;
        __syncthreads();
    }
    if (tid == SCAN_T - 1) bsum[b] = inc;
    const unsigned p0 = inc - tsum;
    if (base < SCAN_TOTAL) {
        *reinterpret_cast<uint4*>(cur + base) =
            make_uint4(p0, p0 + tot[0], p0 + tot[0] + tot[1], p0 + tot[0] + tot[1] + tot[2]);
    }
}

__global__ void k_scan2(const unsigned* __restrict__ bsum, unsigned* __restrict__ boff) {
    __shared__ unsigned s[SCAN_B];
    const int tid = threadIdx.x;
    const unsigned v = bsum[tid];
    s[tid] = v;
    __syncthreads();
    unsigned inc = v;
    for (int d = 1; d < SCAN_B; d <<= 1) {
        unsigned add = (tid >= d) ? s[tid - d] : 0u;
        __syncthreads();
        inc += add;
        s[tid] = inc;
        __syncthreads();
    }
    boff[tid] = inc - v;
}

// ---------------- Phase 2c: chunk+split counting-sort fill -------------------
__global__ __launch_bounds__(256) void k_fill_c(const int* __restrict__ edges,
                                                const unsigned char* __restrict__ cnt2,
                                                const unsigned* __restrict__ cur,
                                                const unsigned* __restrict__ boff,
                                                int* __restrict__ sdst) {
    const int chunk = blockIdx.x, split = blockIdx.y, t = blockIdx.z;
    const int lo = chunk * BPC;
    __shared__ unsigned curl[BPC];
    const size_t o0 = ((size_t)t * CH + chunk) * BPCP;
    for (int i = threadIdx.x; i < BPC; i += 256) {
        int g = t * NN + lo + i;
        unsigned base2 = cur[g] + boff[g >> 10];
        for (int sp = 0; sp < split; sp++)        // block-uniform bound
            base2 += cnt2[(size_t)sp * C2STRIDE + o0 + i];
        curl[i] = base2;
    }
    __syncthreads();
    const int* srcp = edges + (size_t)t * 2 * EE + split * ESL;
    const int* dstp = srcp + EE;   // dst plane is +EE from src plane
    for (int i = threadIdx.x; i < ESL / 4; i += 256) {
        int4 v = reinterpret_cast<const int4*>(srcp)[i];
        int e = i * 4;
        unsigned ux = v.x - lo, uy = v.y - lo, uz = v.z - lo, uw = v.w - lo;
        if (ux < BPC) sdst[atomicAdd(&curl[ux], 1u)] = dstp[e + 0];
        if (uy < BPC) sdst[atomicAdd(&curl[uy], 1u)] = dstp[e + 1];
        if (uz < BPC) sdst[atomicAdd(&curl[uz], 1u)] = dstp[e + 2];
        if (uw < BPC) sdst[atomicAdd(&curl[uw], 1u)] = dstp[e + 3];
    }
}

// ---------------- Phase 2d: per-position src ---------------------------------
__global__ void k_seg(const unsigned* __restrict__ cur, const unsigned* __restrict__ boff,
                      const unsigned* __restrict__ cnt_tot, int* __restrict__ seg) {
    int i = blockIdx.x * blockDim.x + threadIdx.x;
    if (i >= TT * NN) return;
    unsigned start = cur[i] + boff[i >> 10];
    unsigned c = cnt_tot[i];
    int s = i % NN;
    for (unsigned j = 0; j < c; j++) seg[start + j] = s;
}

// ---------------- Phase 3 (v2): node-exclusive blocks, all T per block.
// Block owns nodes [n0, n0+NB): for each t, the sorted edge range for these
// bins is [pos(t*N+n0), pos(t*N+n0+NB)). Accumulate weighted contributions
// into LDS accs[NB][64], write out ONCE non-atomically (no RMW fetch, no
// global atomics at all — kills the 5x out-line ping-pong that was ~all of
// k_edge's 267 MB HBM traffic).
// Barrier-free hot loop: Ab/proj rows [32w,32w+32), src_s/scale_s[e] are all
// wave-private; cross-wave accumulation is LDS atomicAdd (bank-conflict-free:
// lane==feature -> 2-way aliasing, which is free). 4 independent wave
// pipelines per block. -------------------------------------------------------
__global__ __launch_bounds__(256) void k_edge2(
    const unsigned short* __restrict__ xbf, const unsigned short* __restrict__ wT,
    const float* __restrict__ b, const int* __restrict__ sdst,
    const int* __restrict__ seg, const unsigned* __restrict__ cnt,
    const unsigned* __restrict__ cur, const unsigned* __restrict__ boff,
    const float* __restrict__ wgt, float* __restrict__ out) {

    const int n0 = blockIdx.x * NB;
    const int nend = min(n0 + NB, NN);
    const int tid = threadIdx.x;
    const int wv = tid >> 6, lane = tid & 63;
    const int m16 = lane & 15, quad = lane >> 4;

    __shared__ __align__(16) unsigned short Ab[128][136];   // feats tile; reused as f32 proj[128][68]
    __shared__ __align__(16) float accs[NB][64];            // node accumulators
    __shared__ float scale_s[128];
    __shared__ int   src_s[132];                            // padded

    {   // zero node accumulators
        float4* a4 = reinterpret_cast<float4*>(&accs[0][0]);
        for (int i = tid; i < NB * 16; i += 256) a4[i] = make_float4(0.f, 0.f, 0.f, 0.f);
    }
    __syncthreads();

    for (int t = 0; t < TT; t++) {
        const int gbase = t * NN;
        const int g0 = gbase + n0;
        const int g1 = gbase + nend;
        const unsigned p0 = cur[g0] + boff[g0 >> 10];
        const unsigned p1 = (g1 >= TT * NN) ? (unsigned)(TT * EE)
                                            : (cur[g1] + boff[g1 >> 10]);
        const unsigned short* wrow = wT + (size_t)t * 8192;  // [d][k], 64x128
        const float wgt_t = wgt[t];
        float bias[4];
#pragma unroll
        for (int tn = 0; tn < 4; tn++) bias[tn] = b[t * 64 + tn * 16 + m16];

        for (unsigned p = p0; p < p1; p += 128) {
            // gather stage: thread pair per sorted edge (wave-private rows)
            {
                const int e = tid >> 1, half = tid & 1;
                const unsigned pos = p + (unsigned)e;
                float4* l = reinterpret_cast<float4*>(&Ab[e][half * 64]);
                if (pos < p1) {
                    const int idx = half ? sdst[pos] : seg[pos];
                    const float4* g = reinterpret_cast<const float4*>(xbf + (size_t)idx * 64);
#pragma unroll
                    for (int c = 0; c < 8; c++) l[c] = g[c];
                    if (half == 0) {
                        src_s[e] = idx - n0;                          // local node
                        scale_s[e] = wgt_t / (float)cnt[gbase + idx]; // cnt>=1 here
                    }
                } else {
                    const float4 z = make_float4(0.f, 0.f, 0.f, 0.f);
#pragma unroll
                    for (int c = 0; c < 8; c++) l[c] = z;
                    if (half == 0) { src_s[e] = 0; scale_s[e] = 0.f; }
                }
            }
            // NO barrier: this wave wrote exactly rows [wv*32, wv*32+32) and
            // reads only those below.

            f32x4 acc[2][4];
#pragma unroll
            for (int tm = 0; tm < 2; tm++)
#pragma unroll
                for (int tn = 0; tn < 4; tn++)
                    acc[tm][tn] = (f32x4){0.f, 0.f, 0.f, 0.f};

#pragma unroll
            for (int kk = 0; kk < 128; kk += 32) {
                const int kb = kk + quad * 8;
                bf16x8 af[2], bfr[4];
#pragma unroll
                for (int tm = 0; tm < 2; tm++)
                    af[tm] = *reinterpret_cast<const bf16x8*>(&Ab[wv * 32 + tm * 16 + m16][kb]);
#pragma unroll
                for (int tn = 0; tn < 4; tn++)
                    bfr[tn] = *reinterpret_cast<const bf16x8*>(wrow + (tn * 16 + m16) * 128 + kb);
#pragma unroll
                for (int tm = 0; tm < 2; tm++)
#pragma unroll
                    for (int tn = 0; tn < 4; tn++)
                        acc[tm][tn] = __builtin_amdgcn_mfma_f32_16x16x32_bf16(
                            af[tm], bfr[tn], acc[tm][tn], 0, 0, 0);
            }

            // scale + relu, store proj (reusing Ab memory; wave-private rows)
            float* proj = reinterpret_cast<float*>(&Ab[0][0]);   // [128][68] f32
#pragma unroll
            for (int tm = 0; tm < 2; tm++) {
#pragma unroll
                for (int r = 0; r < 4; r++) {
                    const int eloc = wv * 32 + tm * 16 + quad * 4 + r;
                    const float s = scale_s[eloc];
#pragma unroll
                    for (int tn = 0; tn < 4; tn++) {
                        float v = acc[tm][tn][r] + bias[tn];
                        v = v > 0.f ? v : 0.f;
                        proj[eloc * 68 + tn * 16 + m16] = v * s;
                    }
                }
            }

            // wave-cooperative segmented reduce into LDS node accumulators.
            // lane = feature; flush one ds_add burst per segment run.
            {
                const int j0 = wv * 32;
                float sum = 0.f;
#pragma unroll
                for (int j = j0; j < j0 + 32; j++) {
                    sum += proj[j * 68 + lane];
                    const bool flush = (j == j0 + 31) || (src_s[j + 1] != src_s[j]);
                    if (flush) {
                        atomicAdd(&accs[src_s[j]][lane], sum);
                        sum = 0.f;
                    }
                }
            }
        }
    }

    __syncthreads();
    // single coalesced, non-atomic write of the block's exclusive out region
    {
        const int rows = nend - n0;
        const float4* a4 = reinterpret_cast<const float4*>(&accs[0][0]);
        float4* o4 = reinterpret_cast<float4*>(out + (size_t)n0 * 64);
        for (int i = tid; i < rows * 16; i += 256) o4[i] = a4[i];
    }
}

extern "C" void kernel_launch(void* const* d_in, const int* in_sizes, int n_in,
                              void* d_out, int out_size, void* d_ws, size_t ws_size,
                              hipStream_t stream) {
    const float* x     = (const float*)d_in[0];
    const float* W     = (const float*)d_in[1];
    const float* b     = (const float*)d_in[2];
    const float* ea    = (const float*)d_in[3];
    const int*   edges = (const int*)d_in[4];
    float* out = (float*)d_out;

    char* ws = (char*)d_ws;
    unsigned short* xbf  = (unsigned short*)(ws + OFF_XBF);
    unsigned short* wT   = (unsigned short*)(ws + OFF_WT);
    unsigned* cnt_tot    = (unsigned*)(ws + OFF_CTOT);
    float* wgt           = (float*)(ws + OFF_WGT);
    unsigned* cur        = (unsigned*)(ws + OFF_CUR);
    unsigned* bsum       = (unsigned*)(ws + OFF_BS);
    unsigned* boff       = (unsigned*)(ws + OFF_BO);
    unsigned char* cnt2  = (unsigned char*)(ws + OFF_CNT2);
    int* sdst            = (int*)(ws + OFF_DST);
    int* seg             = (int*)(ws + OFF_SEG);

    // Phase 1: x->bf16, W^T, softmax (no out zeroing needed anymore)
    k_init<<<(NN * DD) / 256, 256, 0, stream>>>(x, W, ea, xbf, wT, wgt);

    // Phase 2: chunk+split histogram counts
    dim3 gC(CH, NSPLIT, TT);
    k_count_c<<<gC, 256, 0, stream>>>(edges, cnt2);

    // Phase 2b: per-bin totals + exclusive scan -> cur, boff
    k_scan1<<<SCAN_B, SCAN_T, 0, stream>>>(cnt2, cnt_tot, cur, bsum);
    k_scan2<<<1, SCAN_B, 0, stream>>>(bsum, boff);

    // Phase 2c: chunk+split counting-sort fill
    k_fill_c<<<gC, 256, 0, stream>>>(edges, cnt2, cur, boff, sdst);

    // Phase 2d: per-position src
    k_seg<<<(TT * NN + 255) / 256, 256, 0, stream>>>(cur, boff, cnt_tot, seg);

    // Phase 3: node-exclusive MFMA gather-GEMM, all T per block, atomic-free out
    k_edge2<<<dim3(NBLK), 256, 0, stream>>>(xbf, wT, b, sdst, seg, cnt_tot,
                                            cur, boff, wgt, out);
}

// Round 2
// 339.789 us; speedup vs baseline: 1.7382x; 1.7382x over previous
//
#include <hip/hip_runtime.h>
#include <hip/hip_bf16.h>

#define NN 100000
#define DD 64
#define EE 400000
#define TT 5

#define CH 16                    /* coarse src buckets (chunks) */
#define BPC 6250                 /* NN/CH exact */
#define PSPLIT 32                /* partition slices per t */
#define PESL (EE / PSPLIT)       /* 12,500 edges per slice */
#define PBN (TT * CH * PSPLIT)   /* 2560 partition counters */
#define PB_IDX(t, c, s) ((((t) * CH + (c)) * PSPLIT) + (s))

#define SCAN_TOTAL 500000        /* T*N bins */
#define SCAN_T 256
#define SCAN_PER 1024            /* bins per scan block */
#define SCAN_B 512               /* 512*1024 >= 500000 */

typedef __bf16 bf16x8 __attribute__((ext_vector_type(8)));
typedef float  f32x4  __attribute__((ext_vector_type(4)));

// ws layout (bytes) — total 40,914,240 (unchanged envelope)
#define OFF_XBF  0u            // N*D ushort      = 12,800,000
#define OFF_WT   12800000u     // T*64*128 ushort = 81,920
#define OFF_CTOT 12881920u     // T*N u32 (cnt_tot) = 2,000,000
#define OFF_WGT  14881920u     // T f32 (pad 64)
#define OFF_CUR  14881984u     // T*N u32 (scan of totals) = 2,000,000
#define OFF_BS   16881984u     // 512 u32 (pad 2048)
#define OFF_BO   16884032u     // 512 u32 (pad 2048)
#define OFF_PE   16886080u     // 2M u32 packed (src_local<<17|dst) = 8,000,000
#define OFF_PB   24886080u     // 2561 u32 partition scan (10,244 B, pad to DST)
#define OFF_DST  24914240u     // 2M int (sorted dst) = 8,000,000
#define OFF_SEG  32914240u     // 2M int (seg src)    = 8,000,000 -> 40,914,240

__device__ __forceinline__ unsigned short f2bf(float f) {
    union { float f; unsigned u; } v; v.f = f;
    unsigned u = v.u;
    return (unsigned short)((u + 0x7FFFu + ((u >> 16) & 1u)) >> 16);  // RNE
}

// ---------------- Phase 1: init / convert / out-zero (k_edge atomics need it)
__global__ void k_init(const float* __restrict__ x, const float* __restrict__ W,
                       const float* __restrict__ ea,
                       unsigned short* __restrict__ xbf, unsigned short* __restrict__ wT,
                       float* __restrict__ wgt, float* __restrict__ out) {
    int i = blockIdx.x * blockDim.x + threadIdx.x;   // grid covers N*D exactly
    if (i < NN * DD) {
        out[i] = 0.0f;
        xbf[i] = f2bf(x[i]);
    }
    if (i < TT * 128 * 64) {
        int t = i >> 13;          // /8192
        int rem = i & 8191;
        int d = rem >> 7;         // /128
        int k = rem & 127;
        wT[i] = f2bf(W[t * 8192 + k * 64 + d]);   // wT[t][d][k] = W[t][k][d]
    }
    if (i == 0) {
        float m = -1e30f;
        for (int t = 0; t < TT; t++) m = fmaxf(m, ea[t]);
        float e[TT]; float s = 0.0f;
        for (int t = 0; t < TT; t++) { e[t] = __expf(ea[t] - m); s += e[t]; }
        for (int t = 0; t < TT; t++) wgt[t] = e[t] / s;
    }
}

// ---------------- Phase 2a: coarse 16-bucket counts per (slice, t).
// Each edge read ONCE (vs 16x slice re-reads in the old k_count_c). ----------
__global__ __launch_bounds__(256) void k_pcount(const int* __restrict__ edges,
                                                unsigned* __restrict__ pcnt) {
    const int s = blockIdx.x, t = blockIdx.y;
    __shared__ unsigned h[CH];
    if (threadIdx.x < CH) h[threadIdx.x] = 0u;
    __syncthreads();
    const int4* srcp = reinterpret_cast<const int4*>(edges + (size_t)t * 2 * EE + s * PESL);
    for (int i = threadIdx.x; i < PESL / 4; i += 256) {
        int4 v = srcp[i];
        atomicAdd(&h[(unsigned)v.x / BPC], 1u);
        atomicAdd(&h[(unsigned)v.y / BPC], 1u);
        atomicAdd(&h[(unsigned)v.z / BPC], 1u);
        atomicAdd(&h[(unsigned)v.w / BPC], 1u);
    }
    __syncthreads();
    if (threadIdx.x < CH) pcnt[PB_IDX(t, threadIdx.x, s)] = h[threadIdx.x];
}

// ---------------- Phase 2b: in-place exclusive scan of the 2560 partition
// counters (order: t, chunk, slice — so each (t,chunk) bucket is contiguous
// in pe). Sentinel [2560] = 2,000,000. ---------------------------------------
__global__ void k_pscan(unsigned* __restrict__ pb) {
    __shared__ unsigned s[256];
    const int tid = threadIdx.x;
    unsigned v[10]; unsigned sum = 0u;
#pragma unroll
    for (int j = 0; j < 10; j++) { v[j] = pb[tid * 10 + j]; sum += v[j]; }
    s[tid] = sum;
    __syncthreads();
    unsigned inc = sum;
    for (int d = 1; d < 256; d <<= 1) {
        unsigned a = (tid >= d) ? s[tid - d] : 0u;
        __syncthreads();
        inc += a;
        s[tid] = inc;
        __syncthreads();
    }
    unsigned run = inc - sum;   // exclusive prefix of this thread's 10-group
#pragma unroll
    for (int j = 0; j < 10; j++) { unsigned c = v[j]; pb[tid * 10 + j] = run; run += c; }
    if (tid == 255) pb[PBN] = run;   // sentinel = total (2,000,000)
}

// ---------------- Phase 2c: partition scatter. Packs (src_local:13 | dst:17)
// into one u32 so pe fits the freed 8 MB region. Edges read once. ------------
__global__ __launch_bounds__(256) void k_pscat(const int* __restrict__ edges,
                                               const unsigned* __restrict__ pbase,
                                               unsigned* __restrict__ pe) {
    const int s = blockIdx.x, t = blockIdx.y;
    __shared__ unsigned lofs[CH];
    if (threadIdx.x < CH) lofs[threadIdx.x] = pbase[PB_IDX(t, threadIdx.x, s)];
    __syncthreads();
    const int* srcp = edges + (size_t)t * 2 * EE + s * PESL;
    const int* dstp = srcp + EE;
    for (int i = threadIdx.x; i < PESL / 4; i += 256) {
        int4 v = reinterpret_cast<const int4*>(srcp)[i];
        int4 w = reinterpret_cast<const int4*>(dstp)[i];
        {
            unsigned c = (unsigned)v.x / BPC;
            unsigned o = atomicAdd(&lofs[c], 1u);
            pe[o] = (((unsigned)v.x - c * BPC) << 17) | (unsigned)w.x;
        }
        {
            unsigned c = (unsigned)v.y / BPC;
            unsigned o = atomicAdd(&lofs[c], 1u);
            pe[o] = (((unsigned)v.y - c * BPC) << 17) | (unsigned)w.y;
        }
        {
            unsigned c = (unsigned)v.z / BPC;
            unsigned o = atomicAdd(&lofs[c], 1u);
            pe[o] = (((unsigned)v.z - c * BPC) << 17) | (unsigned)w.z;
        }
        {
            unsigned c = (unsigned)v.w / BPC;
            unsigned o = atomicAdd(&lofs[c], 1u);
            pe[o] = (((unsigned)v.w - c * BPC) << 17) | (unsigned)w.w;
        }
    }
}

// ---------------- Phase 2d: exact per-src counts from bucketed pe ------------
__global__ __launch_bounds__(512) void k_bcount(const unsigned* __restrict__ pe,
                                                const unsigned* __restrict__ pbase,
                                                unsigned* __restrict__ cnt_tot) {
    const int c = blockIdx.x, t = blockIdx.y;
    __shared__ unsigned h[BPC];
    for (int i = threadIdx.x; i < BPC; i += 512) h[i] = 0u;
    __syncthreads();
    const unsigned st = pbase[PB_IDX(t, c, 0)];
    const unsigned en = pbase[((t * CH + c) + 1) * PSPLIT];   // next bucket / sentinel
    for (unsigned i = st + threadIdx.x; i < en; i += 512)
        atomicAdd(&h[pe[i] >> 17], 1u);
    __syncthreads();
    unsigned* outp = cnt_tot + t * NN + c * BPC;
    for (int i = threadIdx.x; i < BPC; i += 512) outp[i] = h[i];
}

// ---------------- Phase 2e: global exclusive scan over T*N bins --------------
__global__ void k_scan1(const unsigned* __restrict__ cnt_tot,
                        unsigned* __restrict__ cur, unsigned* __restrict__ bsum) {
    __shared__ unsigned s[SCAN_T];
    const int b = blockIdx.x, tid = threadIdx.x;
    const int base = b * SCAN_PER + tid * 4;   // bin index (500000 % 4 == 0)
    unsigned tot[4] = {0u, 0u, 0u, 0u};
    if (base < SCAN_TOTAL) {
        uint4 tv = *reinterpret_cast<const uint4*>(cnt_tot + base);
        tot[0] = tv.x; tot[1] = tv.y; tot[2] = tv.z; tot[3] = tv.w;
    }
    const unsigned tsum = tot[0] + tot[1] + tot[2] + tot[3];
    s[tid] = tsum;
    __syncthreads();
    unsigned inc = tsum;
    for (int d = 1; d < SCAN_T; d <<= 1) {
        unsigned add = (tid >= d) ? s[tid - d] : 0u;
        __syncthreads();
        inc += add;
        s[tid] = inc;
        __syncthreads();
    }
    if (tid == SCAN_T - 1) bsum[b] = inc;
    const unsigned p0 = inc - tsum;
    if (base < SCAN_TOTAL) {
        *reinterpret_cast<uint4*>(cur + base) =
            make_uint4(p0, p0 + tot[0], p0 + tot[0] + tot[1], p0 + tot[0] + tot[1] + tot[2]);
    }
}

__global__ void k_scan2(const unsigned* __restrict__ bsum, unsigned* __restrict__ boff) {
    __shared__ unsigned s[SCAN_B];
    const int tid = threadIdx.x;
    const unsigned v = bsum[tid];
    s[tid] = v;
    __syncthreads();
    unsigned inc = v;
    for (int d = 1; d < SCAN_B; d <<= 1) {
        unsigned add = (tid >= d) ? s[tid - d] : 0u;
        __syncthreads();
        inc += add;
        s[tid] = inc;
        __syncthreads();
    }
    boff[tid] = inc - v;
}

// ---------------- Phase 2f: counting-sort fill from pe + FUSED seg write
// (block already holds each bin's start & count — old k_seg eliminated). -----
__global__ __launch_bounds__(512) void k_bfill(const unsigned* __restrict__ pe,
                                               const unsigned* __restrict__ pbase,
                                               const unsigned* __restrict__ cur,
                                               const unsigned* __restrict__ boff,
                                               const unsigned* __restrict__ cnt_tot,
                                               int* __restrict__ sdst,
                                               int* __restrict__ seg) {
    const int c = blockIdx.x, t = blockIdx.y;
    __shared__ unsigned curl[BPC];
    const int n0 = c * BPC;
    for (int i = threadIdx.x; i < BPC; i += 512) {
        int g = t * NN + n0 + i;
        unsigned start = cur[g] + boff[g >> 10];
        curl[i] = start;
        unsigned cc = cnt_tot[g];
        int node = n0 + i;
        for (unsigned j = 0; j < cc; j++) seg[start + j] = node;
    }
    __syncthreads();
    const unsigned st = pbase[PB_IDX(t, c, 0)];
    const unsigned en = pbase[((t * CH + c) + 1) * PSPLIT];
    for (unsigned i = st + threadIdx.x; i < en; i += 512) {
        unsigned p = pe[i];
        sdst[atomicAdd(&curl[p >> 17], 1u)] = (int)(p & 0x1FFFFu);
    }
}

// ---------------- Phase 3: gather -> MFMA -> wave-cooperative segmented scatter.
// EXACT round-0 kernel (proven 184 us): 15625 blocks of TLP hide gather
// latency; R1 proved the t-folded variant starves (occ 19%, 2.1x slower). ----
__global__ __launch_bounds__(256) void k_edge(
    const unsigned short* __restrict__ xbf, const unsigned short* __restrict__ wT,
    const float* __restrict__ b, const int* __restrict__ sdst,
    const int* __restrict__ seg, const unsigned* __restrict__ cnt,
    const float* __restrict__ wgt, float* __restrict__ out) {
    const int t  = blockIdx.y;
    const int e0 = blockIdx.x * 128;

    __shared__ __align__(16) unsigned short Ab[128][136];   // feats tile; reused as f32 proj[128][68]
    __shared__ float scale_s[128];
    __shared__ int   src_s[132];                             // padded

    const int tid = threadIdx.x;

    // stage A: gather x rows (bf16, 128B each); thread pair per sorted edge
    {
        int e = tid >> 1, half = tid & 1;
        size_t pos = (size_t)t * EE + e0 + e;
        int idx = half ? sdst[pos] : seg[pos];
        const float4* g = reinterpret_cast<const float4*>(xbf + (size_t)idx * 64);
        float4* l = reinterpret_cast<float4*>(&Ab[e][half * 64]);
#pragma unroll
        for (int c = 0; c < 8; c++) l[c] = g[c];
        if (half == 0) {
            src_s[e] = idx;
            scale_s[e] = wgt[t] / (float)cnt[t * NN + idx];   // cnt_tot table is L2-hot
        }
    }
    __syncthreads();

    const int wv = tid >> 6, lane = tid & 63;
    const int m16 = lane & 15, quad = lane >> 4;
    const unsigned short* wrow = wT + (size_t)t * 8192;      // [d][k], 64x128

    f32x4 acc[2][4];
#pragma unroll
    for (int tm = 0; tm < 2; tm++)
#pragma unroll
        for (int tn = 0; tn < 4; tn++)
            acc[tm][tn] = (f32x4){0.f, 0.f, 0.f, 0.f};

#pragma unroll
    for (int kk = 0; kk < 128; kk += 32) {
        const int kb = kk + quad * 8;
        bf16x8 af[2], bfr[4];
#pragma unroll
        for (int tm = 0; tm < 2; tm++)
            af[tm] = *reinterpret_cast<const bf16x8*>(&Ab[wv * 32 + tm * 16 + m16][kb]);
#pragma unroll
        for (int tn = 0; tn < 4; tn++)
            bfr[tn] = *reinterpret_cast<const bf16x8*>(wrow + (tn * 16 + m16) * 128 + kb);
#pragma unroll
        for (int tm = 0; tm < 2; tm++)
#pragma unroll
            for (int tn = 0; tn < 4; tn++)
                acc[tm][tn] = __builtin_amdgcn_mfma_f32_16x16x32_bf16(
                    af[tm], bfr[tn], acc[tm][tn], 0, 0, 0);
    }

    // all waves done reading Ab before we overwrite it with f32 proj
    __syncthreads();

    float bias[4];
#pragma unroll
    for (int tn = 0; tn < 4; tn++) bias[tn] = b[t * 64 + tn * 16 + m16];

    float* proj = reinterpret_cast<float*>(&Ab[0][0]);   // [128][68] f32, stride 68
#pragma unroll
    for (int tm = 0; tm < 2; tm++) {
#pragma unroll
        for (int r = 0; r < 4; r++) {
            const int eloc = wv * 32 + tm * 16 + quad * 4 + r;   // in [wv*32, wv*32+32)
            const float s = scale_s[eloc];
#pragma unroll
            for (int tn = 0; tn < 4; tn++) {
                float v = acc[tm][tn][r] + bias[tn];
                v = v > 0.f ? v : 0.f;
                proj[eloc * 68 + tn * 16 + m16] = v * s;
            }
        }
    }
    // NO barrier: wave wv wrote exactly proj rows [wv*32, wv*32+32) and reads
    // only those below. (src_s/scale_s were synced by the earlier barrier.)

    // wave-cooperative segmented reduce: lane = feature, walk 32 sorted edges,
    // flush one COALESCED 256B atomic burst per segment.
    {
        const int j0 = wv * 32;
        float sum = 0.f;
#pragma unroll
        for (int j = j0; j < j0 + 32; j++) {
            sum += proj[j * 68 + lane];
            const bool flush = (j == j0 + 31) || (src_s[j + 1] != src_s[j]);
            if (flush) {
                atomicAdd(out + (size_t)src_s[j] * 64 + lane, sum);
                sum = 0.f;
            }
        }
    }
}

extern "C" void kernel_launch(void* const* d_in, const int* in_sizes, int n_in,
                              void* d_out, int out_size, void* d_ws, size_t ws_size,
                              hipStream_t stream) {
    const float* x     = (const float*)d_in[0];
    const float* W     = (const float*)d_in[1];
    const float* b     = (const float*)d_in[2];
    const float* ea    = (const float*)d_in[3];
    const int*   edges = (const int*)d_in[4];
    float* out = (float*)d_out;

    char* ws = (char*)d_ws;
    unsigned short* xbf  = (unsigned short*)(ws + OFF_XBF);
    unsigned short* wT   = (unsigned short*)(ws + OFF_WT);
    unsigned* cnt_tot    = (unsigned*)(ws + OFF_CTOT);
    float* wgt           = (float*)(ws + OFF_WGT);
    unsigned* cur        = (unsigned*)(ws + OFF_CUR);
    unsigned* bsum       = (unsigned*)(ws + OFF_BS);
    unsigned* boff       = (unsigned*)(ws + OFF_BO);
    unsigned* pe         = (unsigned*)(ws + OFF_PE);
    unsigned* pb         = (unsigned*)(ws + OFF_PB);
    int* sdst            = (int*)(ws + OFF_DST);
    int* seg             = (int*)(ws + OFF_SEG);

    // Phase 1: out-zero, x->bf16, W^T, softmax
    k_init<<<(NN * DD) / 256, 256, 0, stream>>>(x, W, ea, xbf, wT, wgt, out);

    // Phase 2: single-read partition sort (replaces 16x slice re-reading)
    k_pcount<<<dim3(PSPLIT, TT), 256, 0, stream>>>(edges, pb);
    k_pscan<<<1, 256, 0, stream>>>(pb);
    k_pscat<<<dim3(PSPLIT, TT), 256, 0, stream>>>(edges, pb, pe);
    k_bcount<<<dim3(CH, TT), 512, 0, stream>>>(pe, pb, cnt_tot);
    k_scan1<<<SCAN_B, SCAN_T, 0, stream>>>(cnt_tot, cur, bsum);
    k_scan2<<<1, SCAN_B, 0, stream>>>(bsum, boff);
    k_bfill<<<dim3(CH, TT), 512, 0, stream>>>(pe, pb, cur, boff, cnt_tot, sdst, seg);

    // Phase 3: MFMA gather-GEMM + wave-cooperative segmented scatter (round-0)
    dim3 grid(EE / 128, TT);
    k_edge<<<grid, 256, 0, stream>>>(xbf, wT, b, sdst, seg, cnt_tot, wgt, out);
}